// Round 6
// baseline (214.392 us; speedup 1.0000x reference)
//
#include <hip/hip_runtime.h>
#include <hip/hip_bf16.h>

#define N_NODES 30000
#define T_TYPES 4
#define F_DIM   128
#define H_HEADS 8
#define NBLK    ((N_NODES + 31) / 32)   // 938 blocks, 32 consecutive nodes each

typedef __bf16 bf16x8 __attribute__((ext_vector_type(8)));
typedef __bf16 bf16x4 __attribute__((ext_vector_type(4)));
typedef float  floatx4 __attribute__((ext_vector_type(4)));

// ws layout: [0, 131072) node_proj bf16 (4*128*128); [131072, 655360) edge_proj bf16.
#define WS_EPB 131072

// 16-lane (row) sum via DPP on the VALU pipe — no LDS traffic.
template <int CTRL>
static __device__ __forceinline__ float dpp_add(float x) {
    int xi = __builtin_bit_cast(int, x);
    int yi = __builtin_amdgcn_update_dpp(xi, xi, CTRL, 0xF, 0xF, true);
    return x + __builtin_bit_cast(float, yi);
}
static __device__ __forceinline__ float sum16(float x) {
    x = dpp_add<0xB1>(x);    // quad_perm xor1
    x = dpp_add<0x4E>(x);    // quad_perm xor2
    x = dpp_add<0x141>(x);   // row_half_mirror
    x = dpp_add<0x140>(x);   // row_mirror
    return x;
}

// ---- kernel 0: proj tables fp32 -> bf16 (1.25 MB, ~3 us) --------------------
__global__ __launch_bounds__(256) void prep_kernel(
    const float* __restrict__ node_proj, const float* __restrict__ edge_proj,
    __bf16* __restrict__ npb, __bf16* __restrict__ epb)
{
    int i = blockIdx.x * 256 + threadIdx.x;   // 0..81919, each converts 4 floats
    int base = i * 4;
    float4 v;
    __bf16* dst;
    if (base < T_TYPES * F_DIM * F_DIM) {
        v = ((const float4*)node_proj)[i];
        dst = npb + base;
    } else {
        int off = base - T_TYPES * F_DIM * F_DIM;
        v = ((const float4*)edge_proj)[off >> 2];
        dst = epb + off;
    }
    bf16x4 w = { (__bf16)v.x, (__bf16)v.y, (__bf16)v.z, (__bf16)v.w };
    *(bf16x4*)dst = w;
}

// ---- kernel 1: sequential-read main kernel with LOCAL type bucketing --------
// Block: 256 threads (4 waves), 32 CONSECUTIVE nodes. All global input reads
// are sequential (feature 16KB, edge 64KB contiguous per block); type
// divergence resolved in-block via ballot-built perm groups; per type t the
// m-tiles (<=16 rows) share B = proj[t] for MFMA. Out writes 4KB contiguous.
__global__ __launch_bounds__(256, 3) void main_kernel(
    const float* __restrict__ feature, const float* __restrict__ edge_fea,
    const int* __restrict__ mask,
    const __bf16* __restrict__ npb, const __bf16* __restrict__ epb,
    float* __restrict__ out)
{
    const int n0 = blockIdx.x * 32;
    const int valid = min(32, N_NODES - n0);

    // +8 bf16 row pad (16B): rows land 4 banks apart -> 2-way aliasing (free)
    __shared__ __bf16 Afeat[32][136];
    __shared__ __bf16 Aedge[4][32][136];
    __shared__ float  sc[32][4][H_HEADS];
    __shared__ int    perm[32];
    __shared__ int    goff[T_TYPES], gcnt[T_TYPES];

    const int tid = threadIdx.x;

    // ---- local bucket (wave 0): group the 32 nodes by type ----
    if (tid < 64) {
        int lane = tid;
        int t = (lane < valid) ? mask[n0 + lane] : -1;
        int base = 0;
        #pragma unroll
        for (int tt = 0; tt < T_TYPES; ++tt) {
            unsigned long long bm = __ballot(t == tt);
            int cnt = __popcll(bm);
            if (lane == 0) { goff[tt] = base; gcnt[tt] = cnt; }
            if (t == tt) {
                int slot = base + __popcll(bm & ((1ull << lane) - 1ull));
                perm[slot] = lane;
            }
            base += cnt;
        }
    }

    // ---- stage inputs: fully sequential global reads, fp32 -> bf16 LDS ----
    const int colv = tid & 31;     // float4 index within a 128-float row
    const int rowg = tid >> 5;     // 8 rows in flight
    #pragma unroll
    for (int it = 0; it < 4; ++it) {             // 32 feature rows (16KB seq)
        int row = it * 8 + rowg;
        int nl = min(row, valid - 1);
        float4 v = ((const float4*)(feature + (long)(n0 + nl) * F_DIM))[colv];
        bf16x4 w = { (__bf16)v.x, (__bf16)v.y, (__bf16)v.z, (__bf16)v.w };
        *(bf16x4*)(&Afeat[row][0] + colv * 4) = w;
    }
    #pragma unroll
    for (int it = 0; it < 16; ++it) {            // 128 edge rows (64KB seq)
        int r = it * 8 + rowg;                   // r = nl*4 + j (memory order)
        int nl = r >> 2, j = r & 3;
        int nc = min(nl, valid - 1);
        float4 v = ((const float4*)(edge_fea + ((long)(n0 + nc) * 4 + j) * F_DIM))[colv];
        bf16x4 w = { (__bf16)v.x, (__bf16)v.y, (__bf16)v.z, (__bf16)v.w };
        *(bf16x4*)(&Aedge[j][nl][0] + colv * 4) = w;
    }
    __syncthreads();

    const int lane = tid & 63;
    const int wave = tid >> 6;
    const int ml   = lane & 15;
    const int quad = lane >> 4;
    const int g0   = wave * 32;                  // wave covers heads {2w,2w+1}

    // ---- per-type GEMMs + fused score reduction ----
    for (int t = 0; t < T_TYPES; ++t) {          // block-uniform control flow
        const int cnt = gcnt[t];
        if (cnt == 0) continue;
        const int off = goff[t];
        for (int mi = 0; mi * 16 < cnt; ++mi) {
            const int rA = perm[off + min(mi * 16 + ml, cnt - 1)];  // LDS row gather
            // node GEMM: 16 rows x 32 g-cols
            floatx4 accN[2] = {};
            {
                const __bf16* aF = &Afeat[rA][quad * 8];
                const __bf16* b0 = npb + t * (F_DIM * F_DIM) + (g0 + ml) * F_DIM + quad * 8;
                const __bf16* b1 = b0 + 16 * F_DIM;
                #pragma unroll
                for (int k0 = 0; k0 < 128; k0 += 32) {
                    bf16x8 A  = *(const bf16x8*)(aF + k0);
                    bf16x8 B0 = *(const bf16x8*)(b0 + k0);
                    bf16x8 B1 = *(const bf16x8*)(b1 + k0);
                    accN[0] = __builtin_amdgcn_mfma_f32_16x16x32_bf16(A, B0, accN[0], 0, 0, 0);
                    accN[1] = __builtin_amdgcn_mfma_f32_16x16x32_bf16(A, B1, accN[1], 0, 0, 0);
                }
            }
            #pragma unroll
            for (int j = 0; j < 4; ++j) {
                floatx4 accE[2] = {};
                {
                    const __bf16* aE = &Aedge[j][rA][quad * 8];
                    const __bf16* c0 = epb + (t * 4 + j) * (F_DIM * F_DIM) + (g0 + ml) * F_DIM + quad * 8;
                    const __bf16* c1 = c0 + 16 * F_DIM;
                    #pragma unroll
                    for (int k0 = 0; k0 < 128; k0 += 32) {
                        bf16x8 A  = *(const bf16x8*)(aE + k0);
                        bf16x8 B0 = *(const bf16x8*)(c0 + k0);
                        bf16x8 B1 = *(const bf16x8*)(c1 + k0);
                        accE[0] = __builtin_amdgcn_mfma_f32_16x16x32_bf16(A, B0, accE[0], 0, 0, 0);
                        accE[1] = __builtin_amdgcn_mfma_f32_16x16x32_bf16(A, B1, accE[1], 0, 0, 0);
                    }
                }
                // score[slot][h=2w+nt][j] = (1/4) * sum_d node_p*edge_p ; d = lane&15
                #pragma unroll
                for (int nt = 0; nt < 2; ++nt) {
                    floatx4 p = accN[nt] * accE[nt];
                    p.x = sum16(p.x);
                    p.y = sum16(p.y);
                    p.z = sum16(p.z);
                    p.w = sum16(p.w);
                    if (ml == 0) {               // one writer per 16-lane row
                        int h = wave * 2 + nt;
                        int s0 = mi * 16 + quad * 4;   // C/D row = quad*4+reg
                        float pv[4] = { p.x, p.y, p.z, p.w };
                        #pragma unroll
                        for (int i = 0; i < 4; ++i) {
                            int s = s0 + i;
                            if (s < cnt) sc[perm[off + s]][j][h] = pv[i] * 0.25f;
                        }
                    }
                }
            }
        }
    }
    __syncthreads();

    // ---- softmax over heads (axis=1 of [N,H,1,T]) -> out[n][j][h] ----
    if (tid < 128) {
        int node = tid >> 2, j = tid & 3;
        if (node < valid) {
            float v[8], m = -1e30f;
            #pragma unroll
            for (int h = 0; h < 8; ++h) { v[h] = sc[node][j][h]; m = fmaxf(m, v[h]); }
            float s = 0.f;
            #pragma unroll
            for (int h = 0; h < 8; ++h) { v[h] = __expf(v[h] - m); s += v[h]; }
            float r = 1.0f / s;
            float* o = out + (long)(n0 + node) * (T_TYPES * H_HEADS) + j * H_HEADS;
            float4 o0 = { v[0] * r, v[1] * r, v[2] * r, v[3] * r };
            float4 o1 = { v[4] * r, v[5] * r, v[6] * r, v[7] * r };
            ((float4*)o)[0] = o0;
            ((float4*)o)[1] = o1;
        }
    }
}

extern "C" void kernel_launch(void* const* d_in, const int* in_sizes, int n_in,
                              void* d_out, int out_size, void* d_ws, size_t ws_size,
                              hipStream_t stream) {
    const float* feature   = (const float*)d_in[0];
    const float* edge_fea  = (const float*)d_in[1];
    const int*   mask      = (const int*)d_in[2];
    const float* node_proj = (const float*)d_in[3];
    const float* edge_proj = (const float*)d_in[4];
    float* out = (float*)d_out;

    char* ws = (char*)d_ws;
    __bf16* npb = (__bf16*)ws;
    __bf16* epb = (__bf16*)(ws + WS_EPB);

    prep_kernel<<<320, 256, 0, stream>>>(node_proj, edge_proj, npb, epb);
    main_kernel<<<NBLK, 256, 0, stream>>>(feature, edge_fea, mask, npb, epb, out);
}